// Round 2
// baseline (193.097 us; speedup 1.0000x reference)
//
#include <hip/hip_runtime.h>
#include <stdint.h>

#define B_SZ 1024
#define H_SZ 16384
#define SD   32
#define HID  64
#define G_SZ 10
#define K_SZ 4
#define A_SZ 8
#define VA   80         // G*A
#define NC   16         // H chunks
#define CH   (H_SZ/NC)  // 1024

typedef float f32x4  __attribute__((ext_vector_type(4)));
typedef short bf16x8 __attribute__((ext_vector_type(8)));

__device__ inline short f2bf(float a) {
    unsigned u = __float_as_uint(a);
    return (short)((u + 0x7FFFu + ((u >> 16) & 1u)) >> 16);
}
__device__ inline float bf2f(short s) {
    return __uint_as_float(((unsigned)(unsigned short)s) << 16);
}
__device__ inline void split_bf(float v, short& hi, short& lo) {
    hi = f2bf(v);
    lo = f2bf(v - bf2f(hi));
}
__device__ inline int pk_bf16(float a, float b) {
    unsigned ua = __float_as_uint(a), ub = __float_as_uint(b);
    ua = (ua + 0x7FFFu + ((ua >> 16) & 1u)) >> 16;
    ub = (ub + 0x7FFFu + ((ub >> 16) & 1u)) >> 16;
    return (int)(ua | (ub << 16));
}

// ---------------------------------------------------------------------------
// Kernel 1: per-k 3-layer MLP encoders, bf16 hi/lo split MFMA (~fp32 accurate).
// blocks [0,1088): encode; k = bid/272, tile of 64 rows.
// blocks [1088,1216): transpose joint_action [H][80] fp32 -> vt hi/lo bf16 [80][H].
// ---------------------------------------------------------------------------
__global__ __launch_bounds__(256, 2) void k_encode(
    const float* __restrict__ state, const float* __restrict__ hist,
    const float* __restrict__ act,
    const float* __restrict__ W0, const float* __restrict__ b0,
    const float* __restrict__ W1, const float* __restrict__ b1,
    const float* __restrict__ W2, const float* __restrict__ b2,
    short* __restrict__ enc_s_h, short* __restrict__ enc_s_l,
    short* __restrict__ enc_h_h, short* __restrict__ enc_h_l,
    short* __restrict__ vt_h, short* __restrict__ vt_l)
{
    __shared__ __align__(16) short smem[28672];   // 57344 B
    const int bid = blockIdx.x;
    const int t = threadIdx.x;

    if (bid >= 1088) {
        // ---- V transpose role: tile of 128 h rows ----
        short* tile_h = smem;                 // [128][84]
        short* tile_l = smem + 10752;         // [128][84]
        const int h0 = (bid - 1088) * 128;
        for (int i = 0; i < 40; ++i) {
            int idx = t + i * 256;            // 0..10239 coalesced
            float v = act[(size_t)h0 * VA + idx];
            int h = idx / VA, c = idx - h * VA;
            short hh, ll; split_bf(v, hh, ll);
            tile_h[h * 84 + c] = hh;
            tile_l[h * 84 + c] = ll;
        }
        __syncthreads();
        for (int i = 0; i < 5; ++i) {
            int j = t + i * 256;              // 0..1279
            int va = j >> 4, hc = j & 15;
            union { short s[8]; uint4 v; } uh, ul;
            #pragma unroll
            for (int uu = 0; uu < 8; ++uu) {
                uh.s[uu] = tile_h[(hc * 8 + uu) * 84 + va];
                ul.s[uu] = tile_l[(hc * 8 + uu) * 84 + va];
            }
            *(uint4*)(vt_h + (size_t)va * H_SZ + h0 + hc * 8) = uh.v;
            *(uint4*)(vt_l + (size_t)va * H_SZ + h0 + hc * 8) = ul.v;
        }
        return;
    }

    // ---- encode role ----
    const int k = bid / 272;
    const int tl = bid % 272;
    const float* X;
    short *dst_h, *dst_l;
    if (tl < 16) {
        X = state + (size_t)tl * 64 * SD;
        dst_h = enc_s_h + ((size_t)k * B_SZ + tl * 64) * HID;
        dst_l = enc_s_l + ((size_t)k * B_SZ + tl * 64) * HID;
    } else {
        X = hist + (size_t)(tl - 16) * 64 * SD;
        dst_h = enc_h_h + ((size_t)k * H_SZ + (tl - 16) * 64) * HID;
        dst_l = enc_h_l + ((size_t)k * H_SZ + (tl - 16) * 64) * HID;
    }

    // LDS layout (shorts), with lifetime reuse:
    short* xt_h  = smem;            // [64][40]    R1 (dead after L1)
    short* xt_l  = smem + 2560;
    short* wt0_h = smem + 5120;     // [64][40]
    short* wt0_l = smem + 7680;
    short* hb2_h = smem;            // [64][72]    reuse R1 (L2 -> L3)
    short* hb2_l = smem + 4608;
    short* wt1_h = smem + 10240;    // [64][72]    R2 (dead after L2)
    short* wt1_l = smem + 14848;
    short* hb1_h = smem + 19456;    // [64][72]    R4 (L1 -> L2)
    short* hb1_l = smem + 24064;
    short* wt2_h = smem + 19456;    // reuse R4 after L2
    short* wt2_l = smem + 24064;

    const float* W0k = W0 + k * (SD * HID);
    const float* W1k = W1 + k * (HID * HID);
    const float* W2k = W2 + k * (HID * HID);

    { // stage x tile (64x32 fp32 -> hi/lo)
        int r = t >> 2, c0 = (t & 3) * 8;
        const float* src = X + r * SD + c0;
        #pragma unroll
        for (int u = 0; u < 8; ++u) {
            short hh, ll; split_bf(src[u], hh, ll);
            xt_h[r * 40 + c0 + u] = hh;
            xt_l[r * 40 + c0 + u] = ll;
        }
    }
    { // stage W0^T hi/lo
        int i = t >> 3, j0 = (t & 7) * 8;
        #pragma unroll
        for (int u = 0; u < 8; ++u) {
            short hh, ll; split_bf(W0k[i * HID + j0 + u], hh, ll);
            wt0_h[(j0 + u) * 40 + i] = hh;
            wt0_l[(j0 + u) * 40 + i] = ll;
        }
    }
    { // stage W1^T hi/lo
        int i = t >> 2, j0 = (t & 3) * 16;
        #pragma unroll
        for (int u = 0; u < 16; ++u) {
            short hh, ll; split_bf(W1k[i * HID + j0 + u], hh, ll);
            wt1_h[(j0 + u) * 72 + i] = hh;
            wt1_l[(j0 + u) * 72 + i] = ll;
        }
    }
    __syncthreads();

    const int w = t >> 6, l15 = t & 15, quad = (t >> 4) & 3;
    const f32x4 fz = {0.f, 0.f, 0.f, 0.f};

    // Layer 1 (K=32): 3-product split MFMA
    {
        bf16x8 xa_h = *(const bf16x8*)(xt_h + (w * 16 + l15) * 40 + quad * 8);
        bf16x8 xa_l = *(const bf16x8*)(xt_l + (w * 16 + l15) * 40 + quad * 8);
        const float* b0k = b0 + k * HID;
        #pragma unroll
        for (int tt = 0; tt < 4; ++tt) {
            bf16x8 wf_h = *(const bf16x8*)(wt0_h + (l15 + 16 * tt) * 40 + quad * 8);
            bf16x8 wf_l = *(const bf16x8*)(wt0_l + (l15 + 16 * tt) * 40 + quad * 8);
            f32x4 c = __builtin_amdgcn_mfma_f32_16x16x32_bf16(xa_h, wf_h, fz, 0, 0, 0);
            c = __builtin_amdgcn_mfma_f32_16x16x32_bf16(xa_l, wf_h, c, 0, 0, 0);
            c = __builtin_amdgcn_mfma_f32_16x16x32_bf16(xa_h, wf_l, c, 0, 0, 0);
            float bias = b0k[l15 + 16 * tt];
            #pragma unroll
            for (int r = 0; r < 4; ++r) {
                float f = fmaxf(c[r] + bias, 0.f);
                short hh, ll; split_bf(f, hh, ll);
                hb1_h[(w * 16 + quad * 4 + r) * 72 + l15 + 16 * tt] = hh;
                hb1_l[(w * 16 + quad * 4 + r) * 72 + l15 + 16 * tt] = ll;
            }
        }
    }
    __syncthreads();
    // Layer 2 (K=64): writes hb2 into R1 (xt/wt0 dead)
    {
        bf16x8 ha0_h = *(const bf16x8*)(hb1_h + (w * 16 + l15) * 72 + quad * 8);
        bf16x8 ha0_l = *(const bf16x8*)(hb1_l + (w * 16 + l15) * 72 + quad * 8);
        bf16x8 ha1_h = *(const bf16x8*)(hb1_h + (w * 16 + l15) * 72 + 32 + quad * 8);
        bf16x8 ha1_l = *(const bf16x8*)(hb1_l + (w * 16 + l15) * 72 + 32 + quad * 8);
        const float* b1k = b1 + k * HID;
        #pragma unroll
        for (int tt = 0; tt < 4; ++tt) {
            bf16x8 wfa_h = *(const bf16x8*)(wt1_h + (l15 + 16 * tt) * 72 + quad * 8);
            bf16x8 wfa_l = *(const bf16x8*)(wt1_l + (l15 + 16 * tt) * 72 + quad * 8);
            bf16x8 wfb_h = *(const bf16x8*)(wt1_h + (l15 + 16 * tt) * 72 + 32 + quad * 8);
            bf16x8 wfb_l = *(const bf16x8*)(wt1_l + (l15 + 16 * tt) * 72 + 32 + quad * 8);
            f32x4 c = __builtin_amdgcn_mfma_f32_16x16x32_bf16(ha0_h, wfa_h, fz, 0, 0, 0);
            c = __builtin_amdgcn_mfma_f32_16x16x32_bf16(ha1_h, wfb_h, c, 0, 0, 0);
            c = __builtin_amdgcn_mfma_f32_16x16x32_bf16(ha0_l, wfa_h, c, 0, 0, 0);
            c = __builtin_amdgcn_mfma_f32_16x16x32_bf16(ha1_l, wfb_h, c, 0, 0, 0);
            c = __builtin_amdgcn_mfma_f32_16x16x32_bf16(ha0_h, wfa_l, c, 0, 0, 0);
            c = __builtin_amdgcn_mfma_f32_16x16x32_bf16(ha1_h, wfb_l, c, 0, 0, 0);
            float bias = b1k[l15 + 16 * tt];
            #pragma unroll
            for (int r = 0; r < 4; ++r) {
                float f = fmaxf(c[r] + bias, 0.f);
                short hh, ll; split_bf(f, hh, ll);
                hb2_h[(w * 16 + quad * 4 + r) * 72 + l15 + 16 * tt] = hh;
                hb2_l[(w * 16 + quad * 4 + r) * 72 + l15 + 16 * tt] = ll;
            }
        }
    }
    __syncthreads();
    { // stage W2^T hi/lo into hb1's region (hb1 dead)
        int i = t >> 2, j0 = (t & 3) * 16;
        #pragma unroll
        for (int u = 0; u < 16; ++u) {
            short hh, ll; split_bf(W2k[i * HID + j0 + u], hh, ll);
            wt2_h[(j0 + u) * 72 + i] = hh;
            wt2_l[(j0 + u) * 72 + i] = ll;
        }
    }
    __syncthreads();
    // Layer 3 (K=64) -> global hi/lo
    {
        bf16x8 ha0_h = *(const bf16x8*)(hb2_h + (w * 16 + l15) * 72 + quad * 8);
        bf16x8 ha0_l = *(const bf16x8*)(hb2_l + (w * 16 + l15) * 72 + quad * 8);
        bf16x8 ha1_h = *(const bf16x8*)(hb2_h + (w * 16 + l15) * 72 + 32 + quad * 8);
        bf16x8 ha1_l = *(const bf16x8*)(hb2_l + (w * 16 + l15) * 72 + 32 + quad * 8);
        const float* b2k = b2 + k * HID;
        #pragma unroll
        for (int tt = 0; tt < 4; ++tt) {
            bf16x8 wfa_h = *(const bf16x8*)(wt2_h + (l15 + 16 * tt) * 72 + quad * 8);
            bf16x8 wfa_l = *(const bf16x8*)(wt2_l + (l15 + 16 * tt) * 72 + quad * 8);
            bf16x8 wfb_h = *(const bf16x8*)(wt2_h + (l15 + 16 * tt) * 72 + 32 + quad * 8);
            bf16x8 wfb_l = *(const bf16x8*)(wt2_l + (l15 + 16 * tt) * 72 + 32 + quad * 8);
            f32x4 c = __builtin_amdgcn_mfma_f32_16x16x32_bf16(ha0_h, wfa_h, fz, 0, 0, 0);
            c = __builtin_amdgcn_mfma_f32_16x16x32_bf16(ha1_h, wfb_h, c, 0, 0, 0);
            c = __builtin_amdgcn_mfma_f32_16x16x32_bf16(ha0_l, wfa_h, c, 0, 0, 0);
            c = __builtin_amdgcn_mfma_f32_16x16x32_bf16(ha1_l, wfb_h, c, 0, 0, 0);
            c = __builtin_amdgcn_mfma_f32_16x16x32_bf16(ha0_h, wfa_l, c, 0, 0, 0);
            c = __builtin_amdgcn_mfma_f32_16x16x32_bf16(ha1_h, wfb_l, c, 0, 0, 0);
            float bias = b2k[l15 + 16 * tt];
            #pragma unroll
            for (int r = 0; r < 4; ++r) {
                float f = fmaxf(c[r] + bias, 0.f);
                short hh, ll; split_bf(f, hh, ll);
                dst_h[(w * 16 + quad * 4 + r) * HID + l15 + 16 * tt] = hh;
                dst_l[(w * 16 + quad * 4 + r) * HID + l15 + 16 * tt] = ll;
            }
        }
    }
}

// ---------------------------------------------------------------------------
// Kernel 2: flash attention partials with split-precision QK and V.
// grid 512: mtile = bid&7 (128 queries), chunk = (bid>>3)&15, k = bid>>7.
// S = Kh*Qh + Kl*Qh + Kh*Ql (fp32-accurate); PV = (Vh+Vl)*P, P single bf16.
// ---------------------------------------------------------------------------
__global__ __launch_bounds__(256, 2) void k_flash(
    const short* __restrict__ enc_s_h, const short* __restrict__ enc_s_l,
    const short* __restrict__ enc_h_h, const short* __restrict__ enc_h_l,
    const short* __restrict__ vth, const short* __restrict__ vtl,
    float* __restrict__ Pm, float* __restrict__ Pl, float* __restrict__ Pacc)
{
    __shared__ __align__(16) short kh_h[32 * 72];
    __shared__ __align__(16) short kh_l[32 * 72];
    __shared__ __align__(16) short vts_h[80 * 40];
    __shared__ __align__(16) short vts_l[80 * 40];

    const int bid = blockIdx.x;
    const int mtile = bid & 7, chunk = (bid >> 3) & 15, k = bid >> 7;
    const int t = threadIdx.x, w = t >> 6, l15 = t & 15, quad = (t >> 4) & 3;
    const short* ehk_h = enc_h_h + (size_t)k * H_SZ * HID;
    const short* ehk_l = enc_h_l + (size_t)k * H_SZ * HID;
    const int h_base = chunk * CH;
    const int q0 = mtile * 128 + w * 32;
    const float L2E = 1.44269504f;
    const f32x4 fz = {0.f, 0.f, 0.f, 0.f};

    bf16x8 qh[2][2], ql[2][2];
    #pragma unroll
    for (int sub = 0; sub < 2; ++sub)
        #pragma unroll
        for (int kb = 0; kb < 2; ++kb) {
            size_t off = ((size_t)k * B_SZ + q0 + sub * 16 + l15) * HID + kb * 32 + quad * 8;
            qh[sub][kb] = *(const bf16x8*)(enc_s_h + off);
            ql[sub][kb] = *(const bf16x8*)(enc_s_l + off);
        }

    f32x4 acc[2][5];
    #pragma unroll
    for (int s = 0; s < 2; ++s)
        #pragma unroll
        for (int tt = 0; tt < 5; ++tt) acc[s][tt] = fz;
    float mrun[2] = {-__builtin_inff(), -__builtin_inff()};
    float lrun[2] = {0.f, 0.f};

    for (int h0 = h_base; h0 < h_base + CH; h0 += 32) {
        __syncthreads();
        { // stage 32x64 Kh tile hi/lo
            int rr = t >> 3, cc = (t & 7) * 8;
            *(uint4*)(kh_h + rr * 72 + cc) =
                *(const uint4*)(ehk_h + (size_t)(h0 + rr) * HID + cc);
            *(uint4*)(kh_l + rr * 72 + cc) =
                *(const uint4*)(ehk_l + (size_t)(h0 + rr) * HID + cc);
        }
        { // stage V^T tile hi/lo: 80 rows x 32 h
            int va = t >> 2, c = (t & 3) * 8;
            *(uint4*)(vts_h + va * 40 + c) = *(const uint4*)(vth + (size_t)va * H_SZ + h0 + c);
            *(uint4*)(vts_l + va * 40 + c) = *(const uint4*)(vtl + (size_t)va * H_SZ + h0 + c);
            if (t < 64) {
                int va2 = 64 + (t >> 2), c2 = (t & 3) * 8;
                *(uint4*)(vts_h + va2 * 40 + c2) = *(const uint4*)(vth + (size_t)va2 * H_SZ + h0 + c2);
                *(uint4*)(vts_l + va2 * 40 + c2) = *(const uint4*)(vtl + (size_t)va2 * H_SZ + h0 + c2);
            }
        }
        __syncthreads();

        bf16x8 ka_h[2][2], ka_l[2][2];
        #pragma unroll
        for (int hs = 0; hs < 2; ++hs)
            #pragma unroll
            for (int kb = 0; kb < 2; ++kb) {
                ka_h[hs][kb] = *(const bf16x8*)(kh_h + (hs * 16 + l15) * 72 + kb * 32 + quad * 8);
                ka_l[hs][kb] = *(const bf16x8*)(kh_l + (hs * 16 + l15) * 72 + kb * 32 + quad * 8);
            }

        #pragma unroll
        for (int sub = 0; sub < 2; ++sub) {
            f32x4 slo = __builtin_amdgcn_mfma_f32_16x16x32_bf16(ka_h[0][0], qh[sub][0], fz, 0, 0, 0);
            slo = __builtin_amdgcn_mfma_f32_16x16x32_bf16(ka_h[0][1], qh[sub][1], slo, 0, 0, 0);
            slo = __builtin_amdgcn_mfma_f32_16x16x32_bf16(ka_l[0][0], qh[sub][0], slo, 0, 0, 0);
            slo = __builtin_amdgcn_mfma_f32_16x16x32_bf16(ka_l[0][1], qh[sub][1], slo, 0, 0, 0);
            slo = __builtin_amdgcn_mfma_f32_16x16x32_bf16(ka_h[0][0], ql[sub][0], slo, 0, 0, 0);
            slo = __builtin_amdgcn_mfma_f32_16x16x32_bf16(ka_h[0][1], ql[sub][1], slo, 0, 0, 0);
            f32x4 shi = __builtin_amdgcn_mfma_f32_16x16x32_bf16(ka_h[1][0], qh[sub][0], fz, 0, 0, 0);
            shi = __builtin_amdgcn_mfma_f32_16x16x32_bf16(ka_h[1][1], qh[sub][1], shi, 0, 0, 0);
            shi = __builtin_amdgcn_mfma_f32_16x16x32_bf16(ka_l[1][0], qh[sub][0], shi, 0, 0, 0);
            shi = __builtin_amdgcn_mfma_f32_16x16x32_bf16(ka_l[1][1], qh[sub][1], shi, 0, 0, 0);
            shi = __builtin_amdgcn_mfma_f32_16x16x32_bf16(ka_h[1][0], ql[sub][0], shi, 0, 0, 0);
            shi = __builtin_amdgcn_mfma_f32_16x16x32_bf16(ka_h[1][1], ql[sub][1], shi, 0, 0, 0);

            float tm = fmaxf(fmaxf(fmaxf(slo[0], slo[1]), fmaxf(slo[2], slo[3])),
                             fmaxf(fmaxf(shi[0], shi[1]), fmaxf(shi[2], shi[3])));
            tm = fmaxf(tm, __shfl_xor(tm, 16));
            tm = fmaxf(tm, __shfl_xor(tm, 32));
            float mnew = fmaxf(mrun[sub], tm);
            float alpha = exp2f((mrun[sub] - mnew) * L2E);
            float p0 = exp2f((slo[0] - mnew) * L2E), p1 = exp2f((slo[1] - mnew) * L2E);
            float p2 = exp2f((slo[2] - mnew) * L2E), p3 = exp2f((slo[3] - mnew) * L2E);
            float p4 = exp2f((shi[0] - mnew) * L2E), p5 = exp2f((shi[1] - mnew) * L2E);
            float p6 = exp2f((shi[2] - mnew) * L2E), p7 = exp2f((shi[3] - mnew) * L2E);
            float ps = (p0 + p1) + (p2 + p3) + (p4 + p5) + (p6 + p7);
            ps += __shfl_xor(ps, 16);
            ps += __shfl_xor(ps, 32);
            lrun[sub] = lrun[sub] * alpha + ps;
            mrun[sub] = mnew;
            #pragma unroll
            for (int tt = 0; tt < 5; ++tt) acc[sub][tt] = acc[sub][tt] * alpha;

            int plo01 = pk_bf16(p0, p1), plo23 = pk_bf16(p2, p3);
            int phi01 = pk_bf16(p4, p5), phi23 = pk_bf16(p6, p7);
            union { int i[4]; bf16x8 v; } pf;
            #pragma unroll
            for (int jj = 0; jj < 4; ++jj) {
                int src = (((2 * quad + (jj >> 1)) & 3) << 4) + l15;
                int glo = __shfl((jj & 1) ? plo23 : plo01, src);
                int ghi = __shfl((jj & 1) ? phi23 : phi01, src);
                pf.i[jj] = (quad >= 2) ? ghi : glo;
            }
            #pragma unroll
            for (int tt = 0; tt < 5; ++tt) {
                bf16x8 vh = *(const bf16x8*)(vts_h + (l15 + 16 * tt) * 40 + quad * 8);
                bf16x8 vl = *(const bf16x8*)(vts_l + (l15 + 16 * tt) * 40 + quad * 8);
                acc[sub][tt] = __builtin_amdgcn_mfma_f32_16x16x32_bf16(vh, pf.v, acc[sub][tt], 0, 0, 0);
                acc[sub][tt] = __builtin_amdgcn_mfma_f32_16x16x32_bf16(vl, pf.v, acc[sub][tt], 0, 0, 0);
            }
        }
    }

    const int qg = k * B_SZ + q0;
    #pragma unroll
    for (int sub = 0; sub < 2; ++sub) {
        int q = qg + sub * 16 + l15;
        if (quad == 0) {
            Pm[chunk * 4096 + q] = mrun[sub];
            Pl[chunk * 4096 + q] = lrun[sub];
        }
        #pragma unroll
        for (int tt = 0; tt < 5; ++tt)
            #pragma unroll
            for (int r = 0; r < 4; ++r) {
                int va = tt * 16 + quad * 4 + r;
                Pacc[((size_t)chunk * VA + va) * 4096 + q] = acc[sub][tt][r];
            }
    }
}

// ---------------------------------------------------------------------------
// Kernel 3: combine chunk partials per query (q = k*1024 + b).
// ---------------------------------------------------------------------------
__global__ __launch_bounds__(64) void k_reduce1(
    const float* __restrict__ Pm, const float* __restrict__ Pl,
    const float* __restrict__ Pacc, float* __restrict__ O)
{
    const int bid = blockIdx.x;
    const int qb = bid >> 2, vq = bid & 3;
    const int q = qb * 64 + threadIdx.x;
    const float L2E = 1.44269504f;

    float mc[NC];
    float M = -__builtin_inff();
    #pragma unroll
    for (int c = 0; c < NC; ++c) { mc[c] = Pm[c * 4096 + q]; M = fmaxf(M, mc[c]); }
    float wv[NC];
    float L = 0.f;
    #pragma unroll
    for (int c = 0; c < NC; ++c) {
        wv[c] = exp2f((mc[c] - M) * L2E);
        L += wv[c] * Pl[c * 4096 + q];
    }
    float inv = 1.f / L;
    for (int va = vq * 20; va < vq * 20 + 20; ++va) {
        float o = 0.f;
        #pragma unroll
        for (int c = 0; c < NC; ++c)
            o += wv[c] * Pacc[((size_t)c * VA + va) * 4096 + q];
        O[(size_t)q * VA + va] = o * inv;
    }
}

// ---------------------------------------------------------------------------
// Kernel 4: mix abstract agents with softmax(assignment) over k.
// ---------------------------------------------------------------------------
__global__ __launch_bounds__(256) void k_reduce2(
    const float* __restrict__ O, const float* __restrict__ assign,
    float* __restrict__ out)
{
    const int idx = blockIdx.x * 256 + threadIdx.x;   // 81920
    const int b = idx / VA, va = idx - b * VA, g = va >> 3;
    const float L2E = 1.44269504f;
    float a0 = assign[g * K_SZ + 0], a1 = assign[g * K_SZ + 1];
    float a2 = assign[g * K_SZ + 2], a3 = assign[g * K_SZ + 3];
    float mx = fmaxf(fmaxf(a0, a1), fmaxf(a2, a3));
    float e0 = exp2f((a0 - mx) * L2E), e1 = exp2f((a1 - mx) * L2E);
    float e2 = exp2f((a2 - mx) * L2E), e3 = exp2f((a3 - mx) * L2E);
    float inv = 1.f / (e0 + e1 + e2 + e3);
    float o = e0 * O[((size_t)(0 * B_SZ + b)) * VA + va]
            + e1 * O[((size_t)(1 * B_SZ + b)) * VA + va]
            + e2 * O[((size_t)(2 * B_SZ + b)) * VA + va]
            + e3 * O[((size_t)(3 * B_SZ + b)) * VA + va];
    out[idx] = o * inv;
}

extern "C" void kernel_launch(void* const* d_in, const int* in_sizes, int n_in,
                              void* d_out, int out_size, void* d_ws, size_t ws_size,
                              hipStream_t stream)
{
    const float* state  = (const float*)d_in[0];
    const float* hist   = (const float*)d_in[1];
    const float* act    = (const float*)d_in[2];
    const float* W0     = (const float*)d_in[3];
    const float* b0     = (const float*)d_in[4];
    const float* W1     = (const float*)d_in[5];
    const float* b1     = (const float*)d_in[6];
    const float* W2     = (const float*)d_in[7];
    const float* b2     = (const float*)d_in[8];
    const float* assign = (const float*)d_in[9];
    float* out = (float*)d_out;

    char* ws = (char*)d_ws;
    short* enc_s_h = (short*)(ws);                    //   524288 B
    short* enc_s_l = (short*)(ws + 524288);           //   524288 B
    short* enc_h_h = (short*)(ws + 1048576);          //  8388608 B
    short* enc_h_l = (short*)(ws + 9437184);          //  8388608 B
    short* vt_h    = (short*)(ws + 17825792);         //  2621440 B
    short* vt_l    = (short*)(ws + 20447232);         //  2621440 B
    float* Pm      = (float*)(ws + 23068672);         //   262144 B
    float* Pl      = (float*)(ws + 23330816);         //   262144 B
    float* Pacc    = (float*)(ws + 23592960);         // 20971520 B
    float* O       = (float*)(ws + 44564480);         //  1310720 B (total ~43.8 MB)

    k_encode<<<1216, 256, 0, stream>>>(state, hist, act, W0, b0, W1, b1, W2, b2,
                                       enc_s_h, enc_s_l, enc_h_h, enc_h_l, vt_h, vt_l);
    k_flash<<<512, 256, 0, stream>>>(enc_s_h, enc_s_l, enc_h_h, enc_h_l, vt_h, vt_l,
                                     Pm, Pl, Pacc);
    k_reduce1<<<256, 64, 0, stream>>>(Pm, Pl, Pacc, O);
    k_reduce2<<<320, 256, 0, stream>>>(O, assign, out);
}

// Round 3
// 176.628 us; speedup vs baseline: 1.0932x; 1.0932x over previous
//
#include <hip/hip_runtime.h>
#include <stdint.h>

#define B_SZ 1024
#define H_SZ 16384
#define SD   32
#define HID  64
#define G_SZ 10
#define K_SZ 4
#define A_SZ 8
#define VA   80         // G*A
#define NC   16         // H chunks
#define CH   (H_SZ/NC)  // 1024

typedef float f32x4  __attribute__((ext_vector_type(4)));
typedef short bf16x8 __attribute__((ext_vector_type(8)));

__device__ inline short f2bf(float a) {
    unsigned u = __float_as_uint(a);
    return (short)((u + 0x7FFFu + ((u >> 16) & 1u)) >> 16);
}
__device__ inline float bf2f(short s) {
    return __uint_as_float(((unsigned)(unsigned short)s) << 16);
}
__device__ inline void split_bf(float v, short& hi, short& lo) {
    hi = f2bf(v);
    lo = f2bf(v - bf2f(hi));
}
__device__ inline int pk_bf16(float a, float b) {
    unsigned ua = __float_as_uint(a), ub = __float_as_uint(b);
    ua = (ua + 0x7FFFu + ((ua >> 16) & 1u)) >> 16;
    ub = (ub + 0x7FFFu + ((ub >> 16) & 1u)) >> 16;
    return (int)(ua | (ub << 16));
}

// ---------------------------------------------------------------------------
// Kernel 1: per-k 3-layer MLP encoders, bf16 hi/lo split MFMA (~fp32 accurate).
// blocks [0,1088): encode; k = bid/272, tile of 64 rows.
// blocks [1088,1216): transpose joint_action [H][80] fp32 -> vt hi/lo bf16 [80][H].
// ---------------------------------------------------------------------------
__global__ __launch_bounds__(256, 2) void k_encode(
    const float* __restrict__ state, const float* __restrict__ hist,
    const float* __restrict__ act,
    const float* __restrict__ W0, const float* __restrict__ b0,
    const float* __restrict__ W1, const float* __restrict__ b1,
    const float* __restrict__ W2, const float* __restrict__ b2,
    short* __restrict__ enc_s_h, short* __restrict__ enc_s_l,
    short* __restrict__ enc_h_h, short* __restrict__ enc_h_l,
    short* __restrict__ vt_h, short* __restrict__ vt_l)
{
    __shared__ __align__(16) short smem[28672];   // 57344 B
    const int bid = blockIdx.x;
    const int t = threadIdx.x;

    if (bid >= 1088) {
        // ---- V transpose role: tile of 128 h rows ----
        short* tile_h = smem;                 // [128][84]
        short* tile_l = smem + 10752;         // [128][84]
        const int h0 = (bid - 1088) * 128;
        for (int i = 0; i < 40; ++i) {
            int idx = t + i * 256;            // 0..10239 coalesced
            float v = act[(size_t)h0 * VA + idx];
            int h = idx / VA, c = idx - h * VA;
            short hh, ll; split_bf(v, hh, ll);
            tile_h[h * 84 + c] = hh;
            tile_l[h * 84 + c] = ll;
        }
        __syncthreads();
        for (int i = 0; i < 5; ++i) {
            int j = t + i * 256;              // 0..1279
            int va = j >> 4, hc = j & 15;
            union { short s[8]; uint4 v; } uh, ul;
            #pragma unroll
            for (int uu = 0; uu < 8; ++uu) {
                uh.s[uu] = tile_h[(hc * 8 + uu) * 84 + va];
                ul.s[uu] = tile_l[(hc * 8 + uu) * 84 + va];
            }
            *(uint4*)(vt_h + (size_t)va * H_SZ + h0 + hc * 8) = uh.v;
            *(uint4*)(vt_l + (size_t)va * H_SZ + h0 + hc * 8) = ul.v;
        }
        return;
    }

    // ---- encode role ----
    const int k = bid / 272;
    const int tl = bid % 272;
    const float* X;
    short *dst_h, *dst_l;
    if (tl < 16) {
        X = state + (size_t)tl * 64 * SD;
        dst_h = enc_s_h + ((size_t)k * B_SZ + tl * 64) * HID;
        dst_l = enc_s_l + ((size_t)k * B_SZ + tl * 64) * HID;
    } else {
        X = hist + (size_t)(tl - 16) * 64 * SD;
        dst_h = enc_h_h + ((size_t)k * H_SZ + (tl - 16) * 64) * HID;
        dst_l = enc_h_l + ((size_t)k * H_SZ + (tl - 16) * 64) * HID;
    }

    // LDS layout (shorts), with lifetime reuse:
    short* xt_h  = smem;            // [64][40]    R1 (dead after L1)
    short* xt_l  = smem + 2560;
    short* wt0_h = smem + 5120;     // [64][40]
    short* wt0_l = smem + 7680;
    short* hb2_h = smem;            // [64][72]    reuse R1 (L2 -> L3)
    short* hb2_l = smem + 4608;
    short* wt1_h = smem + 10240;    // [64][72]    R2 (dead after L2)
    short* wt1_l = smem + 14848;
    short* hb1_h = smem + 19456;    // [64][72]    R4 (L1 -> L2)
    short* hb1_l = smem + 24064;
    short* wt2_h = smem + 19456;    // reuse R4 after L2
    short* wt2_l = smem + 24064;

    const float* W0k = W0 + k * (SD * HID);
    const float* W1k = W1 + k * (HID * HID);
    const float* W2k = W2 + k * (HID * HID);

    { // stage x tile (64x32 fp32 -> hi/lo)
        int r = t >> 2, c0 = (t & 3) * 8;
        const float* src = X + r * SD + c0;
        #pragma unroll
        for (int u = 0; u < 8; ++u) {
            short hh, ll; split_bf(src[u], hh, ll);
            xt_h[r * 40 + c0 + u] = hh;
            xt_l[r * 40 + c0 + u] = ll;
        }
    }
    { // stage W0^T hi/lo
        int i = t >> 3, j0 = (t & 7) * 8;
        #pragma unroll
        for (int u = 0; u < 8; ++u) {
            short hh, ll; split_bf(W0k[i * HID + j0 + u], hh, ll);
            wt0_h[(j0 + u) * 40 + i] = hh;
            wt0_l[(j0 + u) * 40 + i] = ll;
        }
    }
    { // stage W1^T hi/lo
        int i = t >> 2, j0 = (t & 3) * 16;
        #pragma unroll
        for (int u = 0; u < 16; ++u) {
            short hh, ll; split_bf(W1k[i * HID + j0 + u], hh, ll);
            wt1_h[(j0 + u) * 72 + i] = hh;
            wt1_l[(j0 + u) * 72 + i] = ll;
        }
    }
    __syncthreads();

    const int w = t >> 6, l15 = t & 15, quad = (t >> 4) & 3;
    const f32x4 fz = {0.f, 0.f, 0.f, 0.f};

    // Layer 1 (K=32): 3-product split MFMA
    {
        bf16x8 xa_h = *(const bf16x8*)(xt_h + (w * 16 + l15) * 40 + quad * 8);
        bf16x8 xa_l = *(const bf16x8*)(xt_l + (w * 16 + l15) * 40 + quad * 8);
        const float* b0k = b0 + k * HID;
        #pragma unroll
        for (int tt = 0; tt < 4; ++tt) {
            bf16x8 wf_h = *(const bf16x8*)(wt0_h + (l15 + 16 * tt) * 40 + quad * 8);
            bf16x8 wf_l = *(const bf16x8*)(wt0_l + (l15 + 16 * tt) * 40 + quad * 8);
            f32x4 c = __builtin_amdgcn_mfma_f32_16x16x32_bf16(xa_h, wf_h, fz, 0, 0, 0);
            c = __builtin_amdgcn_mfma_f32_16x16x32_bf16(xa_l, wf_h, c, 0, 0, 0);
            c = __builtin_amdgcn_mfma_f32_16x16x32_bf16(xa_h, wf_l, c, 0, 0, 0);
            float bias = b0k[l15 + 16 * tt];
            #pragma unroll
            for (int r = 0; r < 4; ++r) {
                float f = fmaxf(c[r] + bias, 0.f);
                short hh, ll; split_bf(f, hh, ll);
                hb1_h[(w * 16 + quad * 4 + r) * 72 + l15 + 16 * tt] = hh;
                hb1_l[(w * 16 + quad * 4 + r) * 72 + l15 + 16 * tt] = ll;
            }
        }
    }
    __syncthreads();
    // Layer 2 (K=64): writes hb2 into R1 (xt/wt0 dead)
    {
        bf16x8 ha0_h = *(const bf16x8*)(hb1_h + (w * 16 + l15) * 72 + quad * 8);
        bf16x8 ha0_l = *(const bf16x8*)(hb1_l + (w * 16 + l15) * 72 + quad * 8);
        bf16x8 ha1_h = *(const bf16x8*)(hb1_h + (w * 16 + l15) * 72 + 32 + quad * 8);
        bf16x8 ha1_l = *(const bf16x8*)(hb1_l + (w * 16 + l15) * 72 + 32 + quad * 8);
        const float* b1k = b1 + k * HID;
        #pragma unroll
        for (int tt = 0; tt < 4; ++tt) {
            bf16x8 wfa_h = *(const bf16x8*)(wt1_h + (l15 + 16 * tt) * 72 + quad * 8);
            bf16x8 wfa_l = *(const bf16x8*)(wt1_l + (l15 + 16 * tt) * 72 + quad * 8);
            bf16x8 wfb_h = *(const bf16x8*)(wt1_h + (l15 + 16 * tt) * 72 + 32 + quad * 8);
            bf16x8 wfb_l = *(const bf16x8*)(wt1_l + (l15 + 16 * tt) * 72 + 32 + quad * 8);
            f32x4 c = __builtin_amdgcn_mfma_f32_16x16x32_bf16(ha0_h, wfa_h, fz, 0, 0, 0);
            c = __builtin_amdgcn_mfma_f32_16x16x32_bf16(ha1_h, wfb_h, c, 0, 0, 0);
            c = __builtin_amdgcn_mfma_f32_16x16x32_bf16(ha0_l, wfa_h, c, 0, 0, 0);
            c = __builtin_amdgcn_mfma_f32_16x16x32_bf16(ha1_l, wfb_h, c, 0, 0, 0);
            c = __builtin_amdgcn_mfma_f32_16x16x32_bf16(ha0_h, wfa_l, c, 0, 0, 0);
            c = __builtin_amdgcn_mfma_f32_16x16x32_bf16(ha1_h, wfb_l, c, 0, 0, 0);
            float bias = b1k[l15 + 16 * tt];
            #pragma unroll
            for (int r = 0; r < 4; ++r) {
                float f = fmaxf(c[r] + bias, 0.f);
                short hh, ll; split_bf(f, hh, ll);
                hb2_h[(w * 16 + quad * 4 + r) * 72 + l15 + 16 * tt] = hh;
                hb2_l[(w * 16 + quad * 4 + r) * 72 + l15 + 16 * tt] = ll;
            }
        }
    }
    __syncthreads();
    { // stage W2^T hi/lo into hb1's region (hb1 dead)
        int i = t >> 2, j0 = (t & 3) * 16;
        #pragma unroll
        for (int u = 0; u < 16; ++u) {
            short hh, ll; split_bf(W2k[i * HID + j0 + u], hh, ll);
            wt2_h[(j0 + u) * 72 + i] = hh;
            wt2_l[(j0 + u) * 72 + i] = ll;
        }
    }
    __syncthreads();
    // Layer 3 (K=64) -> global hi/lo
    {
        bf16x8 ha0_h = *(const bf16x8*)(hb2_h + (w * 16 + l15) * 72 + quad * 8);
        bf16x8 ha0_l = *(const bf16x8*)(hb2_l + (w * 16 + l15) * 72 + quad * 8);
        bf16x8 ha1_h = *(const bf16x8*)(hb2_h + (w * 16 + l15) * 72 + 32 + quad * 8);
        bf16x8 ha1_l = *(const bf16x8*)(hb2_l + (w * 16 + l15) * 72 + 32 + quad * 8);
        const float* b2k = b2 + k * HID;
        #pragma unroll
        for (int tt = 0; tt < 4; ++tt) {
            bf16x8 wfa_h = *(const bf16x8*)(wt2_h + (l15 + 16 * tt) * 72 + quad * 8);
            bf16x8 wfa_l = *(const bf16x8*)(wt2_l + (l15 + 16 * tt) * 72 + quad * 8);
            bf16x8 wfb_h = *(const bf16x8*)(wt2_h + (l15 + 16 * tt) * 72 + 32 + quad * 8);
            bf16x8 wfb_l = *(const bf16x8*)(wt2_l + (l15 + 16 * tt) * 72 + 32 + quad * 8);
            f32x4 c = __builtin_amdgcn_mfma_f32_16x16x32_bf16(ha0_h, wfa_h, fz, 0, 0, 0);
            c = __builtin_amdgcn_mfma_f32_16x16x32_bf16(ha1_h, wfb_h, c, 0, 0, 0);
            c = __builtin_amdgcn_mfma_f32_16x16x32_bf16(ha0_l, wfa_h, c, 0, 0, 0);
            c = __builtin_amdgcn_mfma_f32_16x16x32_bf16(ha1_l, wfb_h, c, 0, 0, 0);
            c = __builtin_amdgcn_mfma_f32_16x16x32_bf16(ha0_h, wfa_l, c, 0, 0, 0);
            c = __builtin_amdgcn_mfma_f32_16x16x32_bf16(ha1_h, wfb_l, c, 0, 0, 0);
            float bias = b2k[l15 + 16 * tt];
            #pragma unroll
            for (int r = 0; r < 4; ++r) {
                float f = fmaxf(c[r] + bias, 0.f);
                short hh, ll; split_bf(f, hh, ll);
                dst_h[(w * 16 + quad * 4 + r) * HID + l15 + 16 * tt] = hh;
                dst_l[(w * 16 + quad * 4 + r) * HID + l15 + 16 * tt] = ll;
            }
        }
    }
}

// ---------------------------------------------------------------------------
// Kernel 2: flash attention partials, split-precision, SOFTWARE-PIPELINED.
// grid 512: mtile = bid&7 (128 queries), chunk = (bid>>3)&15, k = bid>>7.
// Per 32-h tile: prefetch next tile into regs during compute; write to LDS
// after the read barrier. S = Kh*Qh + Kl*Qh + Kh*Ql; PV = (Vh+Vl)*P.
// ---------------------------------------------------------------------------
__global__ __launch_bounds__(256, 2) void k_flash(
    const short* __restrict__ enc_s_h, const short* __restrict__ enc_s_l,
    const short* __restrict__ enc_h_h, const short* __restrict__ enc_h_l,
    const short* __restrict__ vth, const short* __restrict__ vtl,
    float* __restrict__ Pm, float* __restrict__ Pl, float* __restrict__ Pacc)
{
    __shared__ __align__(16) short kh_h[32 * 72];
    __shared__ __align__(16) short kh_l[32 * 72];
    __shared__ __align__(16) short vts_h[80 * 40];
    __shared__ __align__(16) short vts_l[80 * 40];

    const int bid = blockIdx.x;
    const int mtile = bid & 7, chunk = (bid >> 3) & 15, k = bid >> 7;
    const int t = threadIdx.x, w = t >> 6, l15 = t & 15, quad = (t >> 4) & 3;
    const short* ehk_h = enc_h_h + (size_t)k * H_SZ * HID;
    const short* ehk_l = enc_h_l + (size_t)k * H_SZ * HID;
    const int h_base = chunk * CH;
    const int q0 = mtile * 128 + w * 32;
    const float L2E = 1.44269504f;
    const f32x4 fz = {0.f, 0.f, 0.f, 0.f};

    bf16x8 qh[2][2], ql[2][2];
    #pragma unroll
    for (int sub = 0; sub < 2; ++sub)
        #pragma unroll
        for (int kb = 0; kb < 2; ++kb) {
            size_t off = ((size_t)k * B_SZ + q0 + sub * 16 + l15) * HID + kb * 32 + quad * 8;
            qh[sub][kb] = *(const bf16x8*)(enc_s_h + off);
            ql[sub][kb] = *(const bf16x8*)(enc_s_l + off);
        }

    f32x4 acc[2][5];
    #pragma unroll
    for (int s = 0; s < 2; ++s)
        #pragma unroll
        for (int tt = 0; tt < 5; ++tt) acc[s][tt] = fz;
    float mrun[2] = {-__builtin_inff(), -__builtin_inff()};
    float lrun[2] = {0.f, 0.f};

    // staging coordinates
    const int krr = t >> 3, kcc = (t & 7) * 8;    // kh: 32 rows x 64
    const int vrw = t >> 2, vcl = (t & 3) * 8;    // vts rows 0..63
    const int vrw2 = 64 + (t >> 2);               // vts rows 64..79 (t<64)

    uint4 pkh, pkl, pvh, pvl, pv2h, pv2l;
    auto load_tile = [&](int h0) {
        pkh = *(const uint4*)(ehk_h + (size_t)(h0 + krr) * HID + kcc);
        pkl = *(const uint4*)(ehk_l + (size_t)(h0 + krr) * HID + kcc);
        pvh = *(const uint4*)(vth + (size_t)vrw * H_SZ + h0 + vcl);
        pvl = *(const uint4*)(vtl + (size_t)vrw * H_SZ + h0 + vcl);
        if (t < 64) {
            pv2h = *(const uint4*)(vth + (size_t)vrw2 * H_SZ + h0 + vcl);
            pv2l = *(const uint4*)(vtl + (size_t)vrw2 * H_SZ + h0 + vcl);
        }
    };
    auto store_tile = [&]() {
        *(uint4*)(kh_h + krr * 72 + kcc) = pkh;
        *(uint4*)(kh_l + krr * 72 + kcc) = pkl;
        *(uint4*)(vts_h + vrw * 40 + vcl) = pvh;
        *(uint4*)(vts_l + vrw * 40 + vcl) = pvl;
        if (t < 64) {
            *(uint4*)(vts_h + vrw2 * 40 + vcl) = pv2h;
            *(uint4*)(vts_l + vrw2 * 40 + vcl) = pv2l;
        }
    };

    load_tile(h_base);
    store_tile();

    for (int it = 0; it < CH / 32; ++it) {
        const int h0 = h_base + it * 32;
        __syncthreads();                      // LDS tile `it` visible to all
        if (it + 1 < CH / 32) load_tile(h0 + 32);   // prefetch overlaps compute

        bf16x8 ka_h[2][2], ka_l[2][2];
        #pragma unroll
        for (int hs = 0; hs < 2; ++hs)
            #pragma unroll
            for (int kb = 0; kb < 2; ++kb) {
                ka_h[hs][kb] = *(const bf16x8*)(kh_h + (hs * 16 + l15) * 72 + kb * 32 + quad * 8);
                ka_l[hs][kb] = *(const bf16x8*)(kh_l + (hs * 16 + l15) * 72 + kb * 32 + quad * 8);
            }

        bf16x8 pfv[2];
        #pragma unroll
        for (int sub = 0; sub < 2; ++sub) {
            f32x4 slo = __builtin_amdgcn_mfma_f32_16x16x32_bf16(ka_h[0][0], qh[sub][0], fz, 0, 0, 0);
            slo = __builtin_amdgcn_mfma_f32_16x16x32_bf16(ka_h[0][1], qh[sub][1], slo, 0, 0, 0);
            slo = __builtin_amdgcn_mfma_f32_16x16x32_bf16(ka_l[0][0], qh[sub][0], slo, 0, 0, 0);
            slo = __builtin_amdgcn_mfma_f32_16x16x32_bf16(ka_l[0][1], qh[sub][1], slo, 0, 0, 0);
            slo = __builtin_amdgcn_mfma_f32_16x16x32_bf16(ka_h[0][0], ql[sub][0], slo, 0, 0, 0);
            slo = __builtin_amdgcn_mfma_f32_16x16x32_bf16(ka_h[0][1], ql[sub][1], slo, 0, 0, 0);
            f32x4 shi = __builtin_amdgcn_mfma_f32_16x16x32_bf16(ka_h[1][0], qh[sub][0], fz, 0, 0, 0);
            shi = __builtin_amdgcn_mfma_f32_16x16x32_bf16(ka_h[1][1], qh[sub][1], shi, 0, 0, 0);
            shi = __builtin_amdgcn_mfma_f32_16x16x32_bf16(ka_l[1][0], qh[sub][0], shi, 0, 0, 0);
            shi = __builtin_amdgcn_mfma_f32_16x16x32_bf16(ka_l[1][1], qh[sub][1], shi, 0, 0, 0);
            shi = __builtin_amdgcn_mfma_f32_16x16x32_bf16(ka_h[1][0], ql[sub][0], shi, 0, 0, 0);
            shi = __builtin_amdgcn_mfma_f32_16x16x32_bf16(ka_h[1][1], ql[sub][1], shi, 0, 0, 0);

            float tm = fmaxf(fmaxf(fmaxf(slo[0], slo[1]), fmaxf(slo[2], slo[3])),
                             fmaxf(fmaxf(shi[0], shi[1]), fmaxf(shi[2], shi[3])));
            tm = fmaxf(tm, __shfl_xor(tm, 16));
            tm = fmaxf(tm, __shfl_xor(tm, 32));
            float mnew = fmaxf(mrun[sub], tm);
            float alpha = exp2f((mrun[sub] - mnew) * L2E);
            float p0 = exp2f((slo[0] - mnew) * L2E), p1 = exp2f((slo[1] - mnew) * L2E);
            float p2 = exp2f((slo[2] - mnew) * L2E), p3 = exp2f((slo[3] - mnew) * L2E);
            float p4 = exp2f((shi[0] - mnew) * L2E), p5 = exp2f((shi[1] - mnew) * L2E);
            float p6 = exp2f((shi[2] - mnew) * L2E), p7 = exp2f((shi[3] - mnew) * L2E);
            float ps = (p0 + p1) + (p2 + p3) + (p4 + p5) + (p6 + p7);
            ps += __shfl_xor(ps, 16);
            ps += __shfl_xor(ps, 32);
            lrun[sub] = lrun[sub] * alpha + ps;
            mrun[sub] = mnew;
            #pragma unroll
            for (int tt = 0; tt < 5; ++tt) acc[sub][tt] = acc[sub][tt] * alpha;

            int plo01 = pk_bf16(p0, p1), plo23 = pk_bf16(p2, p3);
            int phi01 = pk_bf16(p4, p5), phi23 = pk_bf16(p6, p7);
            union { int i[4]; bf16x8 v; } pf;
            #pragma unroll
            for (int jj = 0; jj < 4; ++jj) {
                int src = (((2 * quad + (jj >> 1)) & 3) << 4) + l15;
                int glo = __shfl((jj & 1) ? plo23 : plo01, src);
                int ghi = __shfl((jj & 1) ? phi23 : phi01, src);
                pf.i[jj] = (quad >= 2) ? ghi : glo;
            }
            pfv[sub] = pf.v;
        }

        // Joint PV: one V-fragment read pair serves both subs (10 ds_reads/iter)
        #pragma unroll
        for (int tt = 0; tt < 5; ++tt) {
            bf16x8 vh = *(const bf16x8*)(vts_h + (l15 + 16 * tt) * 40 + quad * 8);
            bf16x8 vl = *(const bf16x8*)(vts_l + (l15 + 16 * tt) * 40 + quad * 8);
            acc[0][tt] = __builtin_amdgcn_mfma_f32_16x16x32_bf16(vh, pfv[0], acc[0][tt], 0, 0, 0);
            acc[0][tt] = __builtin_amdgcn_mfma_f32_16x16x32_bf16(vl, pfv[0], acc[0][tt], 0, 0, 0);
            acc[1][tt] = __builtin_amdgcn_mfma_f32_16x16x32_bf16(vh, pfv[1], acc[1][tt], 0, 0, 0);
            acc[1][tt] = __builtin_amdgcn_mfma_f32_16x16x32_bf16(vl, pfv[1], acc[1][tt], 0, 0, 0);
        }

        __syncthreads();                      // all waves done reading tile `it`
        if (it + 1 < CH / 32) store_tile();   // write prefetched tile
    }

    const int qg = k * B_SZ + q0;
    #pragma unroll
    for (int sub = 0; sub < 2; ++sub) {
        int q = qg + sub * 16 + l15;
        if (quad == 0) {
            Pm[chunk * 4096 + q] = mrun[sub];
            Pl[chunk * 4096 + q] = lrun[sub];
        }
        #pragma unroll
        for (int tt = 0; tt < 5; ++tt)
            #pragma unroll
            for (int r = 0; r < 4; ++r) {
                int va = tt * 16 + quad * 4 + r;
                Pacc[((size_t)chunk * VA + va) * 4096 + q] = acc[sub][tt][r];
            }
    }
}

// ---------------------------------------------------------------------------
// Kernel 3: combine chunk partials per query (q = k*1024 + b).
// grid 320 x 256: bid = qb*5 + vc; thread: q = qb*64+(t&63), 4 va each.
// ---------------------------------------------------------------------------
__global__ __launch_bounds__(256) void k_reduce1(
    const float* __restrict__ Pm, const float* __restrict__ Pl,
    const float* __restrict__ Pacc, float* __restrict__ O)
{
    const int bid = blockIdx.x;
    const int qb = bid / 5, vc = bid - qb * 5;
    const int t = threadIdx.x;
    const int q = qb * 64 + (t & 63);
    const int va0 = vc * 16 + (t >> 6) * 4;
    const float L2E = 1.44269504f;

    float mc[NC];
    float M = -__builtin_inff();
    #pragma unroll
    for (int c = 0; c < NC; ++c) { mc[c] = Pm[c * 4096 + q]; M = fmaxf(M, mc[c]); }
    float wv[NC];
    float L = 0.f;
    #pragma unroll
    for (int c = 0; c < NC; ++c) {
        wv[c] = exp2f((mc[c] - M) * L2E);
        L += wv[c] * Pl[c * 4096 + q];
    }
    float inv = 1.f / L;
    float o[4] = {0.f, 0.f, 0.f, 0.f};
    #pragma unroll
    for (int c = 0; c < NC; ++c) {
        #pragma unroll
        for (int j = 0; j < 4; ++j)
            o[j] += wv[c] * Pacc[((size_t)c * VA + va0 + j) * 4096 + q];
    }
    #pragma unroll
    for (int j = 0; j < 4; ++j)
        O[(size_t)q * VA + va0 + j] = o[j] * inv;
}

// ---------------------------------------------------------------------------
// Kernel 4: mix abstract agents with softmax(assignment) over k.
// ---------------------------------------------------------------------------
__global__ __launch_bounds__(256) void k_reduce2(
    const float* __restrict__ O, const float* __restrict__ assign,
    float* __restrict__ out)
{
    const int idx = blockIdx.x * 256 + threadIdx.x;   // 81920
    const int b = idx / VA, va = idx - b * VA, g = va >> 3;
    const float L2E = 1.44269504f;
    float a0 = assign[g * K_SZ + 0], a1 = assign[g * K_SZ + 1];
    float a2 = assign[g * K_SZ + 2], a3 = assign[g * K_SZ + 3];
    float mx = fmaxf(fmaxf(a0, a1), fmaxf(a2, a3));
    float e0 = exp2f((a0 - mx) * L2E), e1 = exp2f((a1 - mx) * L2E);
    float e2 = exp2f((a2 - mx) * L2E), e3 = exp2f((a3 - mx) * L2E);
    float inv = 1.f / (e0 + e1 + e2 + e3);
    float o = e0 * O[((size_t)(0 * B_SZ + b)) * VA + va]
            + e1 * O[((size_t)(1 * B_SZ + b)) * VA + va]
            + e2 * O[((size_t)(2 * B_SZ + b)) * VA + va]
            + e3 * O[((size_t)(3 * B_SZ + b)) * VA + va];
    out[idx] = o * inv;
}

extern "C" void kernel_launch(void* const* d_in, const int* in_sizes, int n_in,
                              void* d_out, int out_size, void* d_ws, size_t ws_size,
                              hipStream_t stream)
{
    const float* state  = (const float*)d_in[0];
    const float* hist   = (const float*)d_in[1];
    const float* act    = (const float*)d_in[2];
    const float* W0     = (const float*)d_in[3];
    const float* b0     = (const float*)d_in[4];
    const float* W1     = (const float*)d_in[5];
    const float* b1     = (const float*)d_in[6];
    const float* W2     = (const float*)d_in[7];
    const float* b2     = (const float*)d_in[8];
    const float* assign = (const float*)d_in[9];
    float* out = (float*)d_out;

    char* ws = (char*)d_ws;
    short* enc_s_h = (short*)(ws);                    //   524288 B
    short* enc_s_l = (short*)(ws + 524288);           //   524288 B
    short* enc_h_h = (short*)(ws + 1048576);          //  8388608 B
    short* enc_h_l = (short*)(ws + 9437184);          //  8388608 B
    short* vt_h    = (short*)(ws + 17825792);         //  2621440 B
    short* vt_l    = (short*)(ws + 20447232);         //  2621440 B
    float* Pm      = (float*)(ws + 23068672);         //   262144 B
    float* Pl      = (float*)(ws + 23330816);         //   262144 B
    float* Pacc    = (float*)(ws + 23592960);         // 20971520 B
    float* O       = (float*)(ws + 44564480);         //  1310720 B (total ~43.8 MB)

    k_encode<<<1216, 256, 0, stream>>>(state, hist, act, W0, b0, W1, b1, W2, b2,
                                       enc_s_h, enc_s_l, enc_h_h, enc_h_l, vt_h, vt_l);
    k_flash<<<512, 256, 0, stream>>>(enc_s_h, enc_s_l, enc_h_h, enc_h_l, vt_h, vt_l,
                                     Pm, Pl, Pacc);
    k_reduce1<<<320, 256, 0, stream>>>(Pm, Pl, Pacc, O);
    k_reduce2<<<320, 256, 0, stream>>>(O, assign, out);
}